// Round 19
// baseline (14047.954 us; speedup 1.0000x reference)
//
#include <hip/hip_runtime.h>

#define BB    128     // batch
#define TSEQ  256     // time steps
#define DH    1024    // hidden
#define DK2   2048    // concat K
#define NWG   512     // 8 clusters x 64 WGs (normal launch; clusters never cross-wait)
#define NTHR  512

typedef __attribute__((ext_vector_type(8))) short short8;
typedef __attribute__((ext_vector_type(4))) float f32x4;

__device__ __forceinline__ unsigned short f2bf(float f) {
    union { float f; unsigned int u; } v; v.f = f;
    unsigned int r = (v.u + 0x7FFFu + ((v.u >> 16) & 1u)) >> 16;  // RNE
    return (unsigned short)r;
}

__device__ __forceinline__ int imin2(int a, int b) { return a < b ? a : b; }

#define MFMA(a, b, c) __builtin_amdgcn_mfma_f32_16x16x32_bf16((a), (b), (c), 0, 0, 0)

// ---- coherent write-through stores (bypass L1/L2, visible at MALL after vmcnt) ----
__device__ __forceinline__ void cstoref(float* p, float v) {
    asm volatile("global_store_dword %0, %1, off sc0 sc1" :: "v"(p), "v"(v) : "memory");
}
__device__ __forceinline__ void cstoreh(unsigned short* p, unsigned short v) {
    unsigned int w = v;
    asm volatile("global_store_short %0, %1, off sc0 sc1" :: "v"(p), "v"(w) : "memory");
}

// ---- CLUSTER barrier: 64 WGs per cluster (batch-row partition) ----
// Each cluster polls ONLY its own 64 flags => normal launch cannot deadlock.
// INV=1 adds the per-step agent-acquire fence (L2 invalidate) after poll (R12).
template<int INV>
__device__ __forceinline__ void gbar(int* bar, int lg, int wg) {
    asm volatile("s_waitcnt vmcnt(0)" ::: "memory");   // all waves: drain asm stores
    __syncthreads();
    const int tid = threadIdx.x;
    if (tid == 0) {
        int* fp = bar + wg * 16;
        int v = lg + 1;
        asm volatile("global_store_dword %0, %1, off sc0 sc1" :: "v"(fp), "v"(v) : "memory");
    }
    if (tid < 64) {
        const int* f0 = bar + ((wg >> 6) * 64 + tid) * 16;
        const int target = lg + 1;
        for (;;) {
            int a;
            asm volatile("global_load_dword %0, %1, off sc0 sc1" : "=v"(a) : "v"(f0) : "memory");
            asm volatile("s_waitcnt vmcnt(0)" ::: "memory");
            int m = a;
            #pragma unroll
            for (int off = 32; off >= 1; off >>= 1)
                m = imin2(m, __shfl_xor(m, off, 64));
            if (__builtin_amdgcn_readfirstlane(m) >= target) break;
            __builtin_amdgcn_s_sleep(1);
        }
        if (INV) __builtin_amdgcn_fence(__ATOMIC_ACQUIRE, "agent");  // L1+L2 invalidate
    }
    __syncthreads();
}

// ---------------- weight prep + state init ----------------
__global__ __launch_bounds__(256) void prep_weights(const float* __restrict__ W0,
                                                    const float* __restrict__ W1,
                                                    unsigned short* W0f, unsigned short* W0i,
                                                    unsigned short* W0z, unsigned short* Wff,
                                                    unsigned short* Wii, unsigned short* W1z,
                                                    float* h, unsigned short* hb,
                                                    int* bar) {
    int job = blockIdx.x;
    if (job >= 10240) {                     // h, hb zero-init
        int i0 = (job - 10240) * 2048 + threadIdx.x;
        #pragma unroll
        for (int k = 0; k < 8; ++k) { int i = i0 + k * 256; h[i] = 0.f; hb[i] = 0; }
        return;
    }
    if (job == 0) {
        for (int i = threadIdx.x; i < 8192; i += 256) bar[i] = 0;
    }
    __shared__ float tl[32][33];
    const int tx = threadIdx.x & 31, ty = threadIdx.x >> 5;
    if (job < 6144) {                       // W0 gates: 3 x [2048 x 1024] transpose
        int g = job >> 11, r = job & 2047, kt = r >> 5, nt = r & 31;
        const float* src = W0 + (size_t)g * DK2 * DH;
        unsigned short* dst = (g == 0) ? W0f : ((g == 1) ? W0i : W0z);
        #pragma unroll
        for (int i = 0; i < 4; ++i)
            tl[ty + i * 8][tx] = src[(size_t)(kt * 32 + ty + i * 8) * DH + nt * 32 + tx];
        __syncthreads();
        #pragma unroll
        for (int i = 0; i < 4; ++i)
            dst[(size_t)(nt * 32 + ty + i * 8) * DK2 + kt * 32 + tx] = f2bf(tl[tx][ty + i * 8]);
    } else if (job < 8192) {                // W1 f,i folded: [1024][1024]
        int r = job - 6144; int g = r >> 10; r &= 1023;
        int kt = r >> 5, nt = r & 31;
        const float* src = W1 + (size_t)g * DK2 * DH;
        unsigned short* dst = (g == 0) ? Wff : Wii;
        #pragma unroll
        for (int i = 0; i < 4; ++i)
            tl[ty + i * 8][tx] = src[(size_t)(kt * 32 + ty + i * 8) * DH + nt * 32 + tx]
                               + src[(size_t)(1024 + kt * 32 + ty + i * 8) * DH + nt * 32 + tx];
        __syncthreads();
        #pragma unroll
        for (int i = 0; i < 4; ++i)
            dst[(size_t)(nt * 32 + ty + i * 8) * DH + kt * 32 + tx] = f2bf(tl[tx][ty + i * 8]);
    } else {                                // W1 z: [2048 x 1024] transpose
        int r = job - 8192; int kt = r >> 5, nt = r & 31;
        const float* src = W1 + (size_t)2 * DK2 * DH;
        #pragma unroll
        for (int i = 0; i < 4; ++i)
            tl[ty + i * 8][tx] = src[(size_t)(kt * 32 + ty + i * 8) * DH + nt * 32 + tx];
        __syncthreads();
        #pragma unroll
        for (int i = 0; i < 4; ++i)
            W1z[(size_t)(nt * 32 + ty + i * 8) * DK2 + kt * 32 + tx] = f2bf(tl[tx][ty + i * 8]);
    }
}

// ---------------- main persistent kernel ----------------
struct GruParams {
    const float* x;
    const float* b0;
    const float* b1;
    const unsigned short* W0f;      // [1024 n][2048 k]
    const unsigned short* W0i;
    const unsigned short* W0z;
    const unsigned short* Wff;      // [1024][1024] folded
    const unsigned short* Wii;
    const unsigned short* W1z;      // [1024 n][2048 k]
    float* xpre;                    // [32][128][3072] f32
    float* h;  unsigned short* hb;
    float* fg;
    unsigned short* hib;
    float* h1;
    unsigned short* hcat;           // [128][2048] bf16: [h1 | h1*i2]
    float* f2g;
    float* out;
    int* bar;
};

// amdgpu_waves_per_eu(4,4): pin the allocator to EXACTLY 4 waves/EU (128 VGPR
// budget). R16/R17 showed launch_bounds(512,4) alone lets the backend target
// 8 waves/EU (64 VGPRs), which serialized (R16) or spilled (R17) the phase's
// batched loads. 2 blocks/CU co-residency needs exactly 16 waves/CU = 4/EU.
__global__ __launch_bounds__(NTHR) __attribute__((amdgpu_waves_per_eu(4, 4)))
void gru_main(GruParams P) {
    const int wg   = blockIdx.x;
    const int c    = wg >> 6;          // cluster 0..7, owns batch rows [16c, 16c+16)
    const int cwg  = wg & 63;          // WG within cluster
    const int tid  = threadIdx.x;
    const int lane = tid & 63;
    const int wv   = tid >> 6;         // 0..7
    const int cw   = wv & 1, ks4 = wv >> 1;   // A/C: 2 col-halves x 4-way ksplit
    const int lr   = lane & 15;
    const int kb   = (lane >> 4) * 8;  // k-offset within frag
    const int drow = (lane >> 4) * 4;  // D-frag row base

    __shared__ float s_red[7][16][17];     // shared reduce: A/C slots 0..5, B/D slots 0..6

    int lg = 0;
    const int crow = c * 16;           // cluster's batch-row base

    const int gateAC = cwg >> 5, nctAC = cwg & 31;   // A/C: 2 gates x 32 col-tiles (16x32)
    const int colBD  = cwg * 16;                     // B/D: 64 col-tiles (16x16)

    for (int t = 0; t < TSEQ; ++t) {
        // ---- chunk GEMM every 32 steps (cluster rows x all 3072 cols) ----
        if ((t & 31) == 0) {
            for (int j = cwg; j < 384; j += 64) {
                int tt = j / 12, cj = j % 12;          // 12 col-blocks of 256
                int g = cj >> 2;
                int gcol0 = (cj & 3) * 256 + wv * 32;  // 32 cols per wave
                int b = crow + lr;
                const float* xp = P.x + ((size_t)b * TSEQ + (t + tt)) * DH + kb;
                const unsigned short* wt = (g == 0) ? P.W0f : ((g == 1) ? P.W0i : P.W0z);
                const unsigned short* wp0 = wt + (size_t)(gcol0 + lr) * DK2 + kb;
                const unsigned short* wp1 = wt + (size_t)(gcol0 + 16 + lr) * DK2 + kb;
                f32x4 a0 = {0,0,0,0}, a1 = a0;
                #pragma unroll 2
                for (int k = 0; k < DH; k += 32) {
                    f32x4 lo = *(const f32x4*)(xp + k);
                    f32x4 hi = *(const f32x4*)(xp + k + 4);
                    short8 av;
                    av[0] = (short)f2bf(lo[0]); av[1] = (short)f2bf(lo[1]);
                    av[2] = (short)f2bf(lo[2]); av[3] = (short)f2bf(lo[3]);
                    av[4] = (short)f2bf(hi[0]); av[5] = (short)f2bf(hi[1]);
                    av[6] = (short)f2bf(hi[2]); av[7] = (short)f2bf(hi[3]);
                    short8 b0v = *(const short8*)(wp0 + k);
                    short8 b1v = *(const short8*)(wp1 + k);
                    a0 = MFMA(av, b0v, a0);
                    a1 = MFMA(av, b1v, a1);
                }
                int rowb = tt * 128 + crow + drow;
                #pragma unroll
                for (int cf = 0; cf < 2; ++cf) {
                    f32x4 acc = cf ? a1 : a0;
                    int col = g * DH + gcol0 + cf * 16 + lr;
                    #pragma unroll
                    for (int rr = 0; rr < 4; ++rr)
                        cstoref(P.xpre + (size_t)(rowb + rr) * 3072 + col, acc[rr]);
                }
            }
            gbar<0>(P.bar, lg, wg); ++lg;
        }
        const int tq = t & 31;

        // ---- Phase A: L1 f,i = sigmoid(xpre + h @ W0{f,i}[h-part] + b0) ----
        // 16x32 tile per WG: 2 col-halves (cw) x 4-way ksplit (ks4)
        {
            const int gate = gateAC;
            const unsigned short* wt = gate ? P.W0i : P.W0f;
            const int colb = nctAC * 32 + cw * 16;
            const unsigned short* ap = P.hb + (size_t)(crow + lr) * DH + ks4 * 256 + kb;
            const unsigned short* wp = wt + (size_t)(colb + lr) * DK2 + 1024 + ks4 * 256 + kb;
            int n = colb + lr;
            short8 a[8];
            #pragma unroll
            for (int k = 0; k < 8; ++k) a[k] = *(const short8*)(ap + (size_t)k * 32);
            float xv[4] = {0,0,0,0}, hv[4] = {0,0,0,0};
            if (ks4 == 0) {
                #pragma unroll
                for (int rr = 0; rr < 4; ++rr)
                    xv[rr] = P.xpre[(size_t)(tq * 128 + crow + drow + rr) * 3072 + gate * DH + n];
                if (gate == 1) {
                    #pragma unroll
                    for (int rr = 0; rr < 4; ++rr)
                        hv[rr] = P.h[(size_t)(crow + drow + rr) * DH + n];
                }
            }
            short8 bw[8];
            #pragma unroll
            for (int k = 0; k < 8; ++k) bw[k] = *(const short8*)(wp + (size_t)k * 32);
            f32x4 acc = {0.f, 0.f, 0.f, 0.f};
            #pragma unroll
            for (int k = 0; k < 8; ++k) acc = MFMA(a[k], bw[k], acc);
            if (ks4 != 0) {
                int slot = cw * 3 + ks4 - 1;
                #pragma unroll
                for (int rr = 0; rr < 4; ++rr) s_red[slot][drow + rr][lr] = acc[rr];
            }
            __syncthreads();
            if (ks4 == 0) {
                #pragma unroll
                for (int rr = 0; rr < 4; ++rr)
                    acc[rr] += s_red[cw * 3 + 0][drow + rr][lr] + s_red[cw * 3 + 1][drow + rr][lr]
                             + s_red[cw * 3 + 2][drow + rr][lr];
                float bias = P.b0[gate * DH + n];
                #pragma unroll
                for (int rr = 0; rr < 4; ++rr) {
                    int b = crow + drow + rr;
                    float pre = acc[rr] + xv[rr] + bias;
                    float s = 1.f / (1.f + __expf(-pre));
                    if (gate == 0) cstoref(P.fg + (size_t)b * DH + n, s);
                    else           cstoreh(P.hib + (size_t)b * DH + n, f2bf(hv[rr] * s));
                }
            }
            gbar<0>(P.bar, lg, wg); ++lg;
        }

        // ---- Phase B: L1 z = tanh(xpre_z + (h*i) @ W0z[h-part] + b0z); h1 = (1-f)h + f z ----
        // 16x16 tile per WG: 8-way ksplit (wv), 128 k-els each
        {
            const unsigned short* ap = P.hib + (size_t)(crow + lr) * DH + wv * 128 + kb;
            const unsigned short* wp = P.W0z + (size_t)(colBD + lr) * DK2 + 1024 + wv * 128 + kb;
            int n = colBD + lr;
            short8 a[4];
            #pragma unroll
            for (int k = 0; k < 4; ++k) a[k] = *(const short8*)(ap + (size_t)k * 32);
            float xv[4] = {0,0,0,0}, fv[4] = {0,0,0,0}, hv[4] = {0,0,0,0};
            if (wv == 0) {
                #pragma unroll
                for (int rr = 0; rr < 4; ++rr) {
                    int b = crow + drow + rr;
                    xv[rr] = P.xpre[(size_t)(tq * 128 + b) * 3072 + 2 * DH + n];
                    fv[rr] = P.fg[(size_t)b * DH + n];
                    hv[rr] = P.h[(size_t)b * DH + n];
                }
            }
            short8 bw[4];
            #pragma unroll
            for (int k = 0; k < 4; ++k) bw[k] = *(const short8*)(wp + (size_t)k * 32);
            f32x4 acc = {0.f, 0.f, 0.f, 0.f};
            #pragma unroll
            for (int k = 0; k < 4; ++k) acc = MFMA(a[k], bw[k], acc);
            if (wv != 0) {
                #pragma unroll
                for (int rr = 0; rr < 4; ++rr) s_red[wv - 1][drow + rr][lr] = acc[rr];
            }
            __syncthreads();
            if (wv == 0) {
                #pragma unroll
                for (int j = 0; j < 7; ++j)
                    #pragma unroll
                    for (int rr = 0; rr < 4; ++rr) acc[rr] += s_red[j][drow + rr][lr];
                float bias = P.b0[2 * DH + n];
                #pragma unroll
                for (int rr = 0; rr < 4; ++rr) {
                    int b = crow + drow + rr;
                    float pre = acc[rr] + xv[rr] + bias;
                    float z = tanhf(pre);
                    float nh = (1.f - fv[rr]) * hv[rr] + fv[rr] * z;
                    cstoref(P.h1 + (size_t)b * DH + n, nh);
                    cstoreh(P.hcat + (size_t)b * DK2 + n, f2bf(nh));
                }
            }
            gbar<0>(P.bar, lg, wg); ++lg;
        }

        // ---- Phase C: L2 f2 = sigmoid(h1 @ Wff + b1f), i2 = sigmoid(h1 @ Wii + b1i) ----
        {
            const int gate = gateAC;
            const unsigned short* wt = gate ? P.Wii : P.Wff;
            const int colb = nctAC * 32 + cw * 16;
            const unsigned short* ap = P.hcat + (size_t)(crow + lr) * DK2 + ks4 * 256 + kb;
            const unsigned short* wp = wt + (size_t)(colb + lr) * DH + ks4 * 256 + kb;
            int n = colb + lr;
            short8 a[8];
            #pragma unroll
            for (int k = 0; k < 8; ++k) a[k] = *(const short8*)(ap + (size_t)k * 32);
            float h1v[4] = {0,0,0,0};
            if (ks4 == 0 && gate == 1) {
                #pragma unroll
                for (int rr = 0; rr < 4; ++rr)
                    h1v[rr] = P.h1[(size_t)(crow + drow + rr) * DH + n];
            }
            short8 bw[8];
            #pragma unroll
            for (int k = 0; k < 8; ++k) bw[k] = *(const short8*)(wp + (size_t)k * 32);
            f32x4 acc = {0.f, 0.f, 0.f, 0.f};
            #pragma unroll
            for (int k = 0; k < 8; ++k) acc = MFMA(a[k], bw[k], acc);
            if (ks4 != 0) {
                int slot = cw * 3 + ks4 - 1;
                #pragma unroll
                for (int rr = 0; rr < 4; ++rr) s_red[slot][drow + rr][lr] = acc[rr];
            }
            __syncthreads();
            if (ks4 == 0) {
                #pragma unroll
                for (int rr = 0; rr < 4; ++rr)
                    acc[rr] += s_red[cw * 3 + 0][drow + rr][lr] + s_red[cw * 3 + 1][drow + rr][lr]
                             + s_red[cw * 3 + 2][drow + rr][lr];
                float bias = P.b1[gate * DH + n];
                #pragma unroll
                for (int rr = 0; rr < 4; ++rr) {
                    int b = crow + drow + rr;
                    float pre = acc[rr] + bias;
                    float s = 1.f / (1.f + __expf(-pre));
                    if (gate == 0) cstoref(P.f2g + (size_t)b * DH + n, s);
                    else           cstoreh(P.hcat + (size_t)b * DK2 + DH + n, f2bf(h1v[rr] * s));
                }
            }
            gbar<0>(P.bar, lg, wg); ++lg;
        }

        // ---- Phase D: z2 = tanh([h1 | h1*i2] @ W1z + b1z); h = (1-f2)h1 + f2 z2 ----
        // 16x16 tile per WG: 8-way ksplit over K=2048, 256 k-els each
        {
            const unsigned short* ap = P.hcat + (size_t)(crow + lr) * DK2 + wv * 256 + kb;
            const unsigned short* wp = P.W1z + (size_t)(colBD + lr) * DK2 + wv * 256 + kb;
            int n = colBD + lr;
            short8 a[8];
            #pragma unroll
            for (int k = 0; k < 8; ++k) a[k] = *(const short8*)(ap + (size_t)k * 32);
            float f2v[4] = {0,0,0,0}, h1v[4] = {0,0,0,0};
            if (wv == 0) {
                #pragma unroll
                for (int rr = 0; rr < 4; ++rr) {
                    int b = crow + drow + rr;
                    f2v[rr] = P.f2g[(size_t)b * DH + n];
                    h1v[rr] = P.h1[(size_t)b * DH + n];
                }
            }
            short8 bw[8];
            #pragma unroll
            for (int k = 0; k < 8; ++k) bw[k] = *(const short8*)(wp + (size_t)k * 32);
            f32x4 acc = {0.f, 0.f, 0.f, 0.f};
            #pragma unroll
            for (int k = 0; k < 8; ++k) acc = MFMA(a[k], bw[k], acc);
            if (wv != 0) {
                #pragma unroll
                for (int rr = 0; rr < 4; ++rr) s_red[wv - 1][drow + rr][lr] = acc[rr];
            }
            __syncthreads();
            if (wv == 0) {
                #pragma unroll
                for (int j = 0; j < 7; ++j)
                    #pragma unroll
                    for (int rr = 0; rr < 4; ++rr) acc[rr] += s_red[j][drow + rr][lr];
                float bias = P.b1[2 * DH + n];
                #pragma unroll
                for (int rr = 0; rr < 4; ++rr) {
                    int b = crow + drow + rr;
                    float pre = acc[rr] + bias;
                    float z = tanhf(pre);
                    float nh = (1.f - f2v[rr]) * h1v[rr] + f2v[rr] * z;
                    cstoref(P.h + (size_t)b * DH + n, nh);
                    cstoreh(P.hb + (size_t)b * DH + n, f2bf(nh));
                    if (t == TSEQ - 1) P.out[(size_t)b * DH + n] = nh;  // normal store: kernel-end flush
                }
            }
            gbar<1>(P.bar, lg, wg); ++lg;   // step boundary: L2 invalidate
        }
    }
}

extern "C" void kernel_launch(void* const* d_in, const int* in_sizes, int n_in,
                              void* d_out, int out_size, void* d_ws, size_t ws_size,
                              hipStream_t stream) {
    const float* x  = (const float*)d_in[0];
    const float* W0 = (const float*)d_in[1];
    const float* b0 = (const float*)d_in[2];
    const float* W1 = (const float*)d_in[3];
    const float* b1 = (const float*)d_in[4];

    char* ws = (char*)d_ws;
    size_t off = 0;
    auto alloc = [&](size_t bytes) { void* p = ws + off; off += (bytes + 255) & ~(size_t)255; return p; };

    unsigned short* W0f = (unsigned short*)alloc((size_t)DH * DK2 * 2);
    unsigned short* W0i = (unsigned short*)alloc((size_t)DH * DK2 * 2);
    unsigned short* W0z = (unsigned short*)alloc((size_t)DH * DK2 * 2);
    unsigned short* W1z = (unsigned short*)alloc((size_t)DH * DK2 * 2);
    unsigned short* Wff = (unsigned short*)alloc((size_t)DH * DH * 2);
    unsigned short* Wii = (unsigned short*)alloc((size_t)DH * DH * 2);
    float* xpre = (float*)alloc((size_t)32 * 128 * 3072 * 4);
    float* h    = (float*)alloc((size_t)BB * DH * 4);
    unsigned short* hb = (unsigned short*)alloc((size_t)BB * DH * 2);
    float* fg   = (float*)alloc((size_t)BB * DH * 4);
    unsigned short* hib = (unsigned short*)alloc((size_t)BB * DH * 2);
    float* h1   = (float*)alloc((size_t)BB * DH * 4);
    unsigned short* hcat = (unsigned short*)alloc((size_t)BB * DK2 * 2);
    float* f2g  = (float*)alloc((size_t)BB * DH * 4);
    int* bar    = (int*)alloc(32768);
    (void)ws_size; (void)in_sizes; (void)n_in; (void)out_size;

    prep_weights<<<10304, 256, 0, stream>>>(W0, W1, W0f, W0i, W0z, Wff, Wii, W1z,
                                            h, hb, bar);

    GruParams p;
    p.x = x; p.b0 = b0; p.b1 = b1;
    p.W0f = W0f; p.W0i = W0i; p.W0z = W0z; p.Wff = Wff; p.Wii = Wii; p.W1z = W1z;
    p.xpre = xpre; p.h = h; p.hb = hb; p.fg = fg; p.hib = hib;
    p.h1 = h1; p.hcat = hcat; p.f2g = f2g;
    p.out = (float*)d_out;
    p.bar = bar;

    gru_main<<<NWG, NTHR, 0, stream>>>(p);
}

// Round 20
// 11123.582 us; speedup vs baseline: 1.2629x; 1.2629x over previous
//
#include <hip/hip_runtime.h>

#define BB    128     // batch
#define TSEQ  256     // time steps
#define DH    1024    // hidden
#define DK2   2048    // concat K
#define NWG   256
#define NTHR  512

typedef __attribute__((ext_vector_type(8))) short short8;
typedef __attribute__((ext_vector_type(4))) float f32x4;

__device__ __forceinline__ unsigned short f2bf(float f) {
    union { float f; unsigned int u; } v; v.f = f;
    unsigned int r = (v.u + 0x7FFFu + ((v.u >> 16) & 1u)) >> 16;  // RNE
    return (unsigned short)r;
}

__device__ __forceinline__ int imin2(int a, int b) { return a < b ? a : b; }

#define MFMA(a, b, c) __builtin_amdgcn_mfma_f32_16x16x32_bf16((a), (b), (c), 0, 0, 0)

// ---- coherent write-through stores (bypass L1/L2, visible at MALL after vmcnt) ----
__device__ __forceinline__ void cstoref(float* p, float v) {
    asm volatile("global_store_dword %0, %1, off sc0 sc1" :: "v"(p), "v"(v) : "memory");
}
__device__ __forceinline__ void cstoreh(unsigned short* p, unsigned short v) {
    unsigned int w = v;
    asm volatile("global_store_short %0, %1, off sc0 sc1" :: "v"(p), "v"(w) : "memory");
}

// ---- CLUSTER barrier: 64 WGs per cluster (batch-row partition) — R13-proven ----
// INV=1 adds the per-step agent-acquire fence (L2 invalidate) after poll (R12).
template<int INV>
__device__ __forceinline__ void gbar(int* bar, int lg, int wg) {
    asm volatile("s_waitcnt vmcnt(0)" ::: "memory");   // all waves: drain asm stores
    __syncthreads();
    const int tid = threadIdx.x;
    if (tid == 0) {
        int* fp = bar + wg * 16;
        int v = lg + 1;
        asm volatile("global_store_dword %0, %1, off sc0 sc1" :: "v"(fp), "v"(v) : "memory");
    }
    if (tid < 64) {
        const int* f0 = bar + ((wg >> 6) * 64 + tid) * 16;
        const int target = lg + 1;
        for (;;) {
            int a;
            asm volatile("global_load_dword %0, %1, off sc0 sc1" : "=v"(a) : "v"(f0) : "memory");
            asm volatile("s_waitcnt vmcnt(0)" ::: "memory");
            int m = a;
            #pragma unroll
            for (int off = 32; off >= 1; off >>= 1)
                m = imin2(m, __shfl_xor(m, off, 64));
            if (__builtin_amdgcn_readfirstlane(m) >= target) break;
            __builtin_amdgcn_s_sleep(1);
        }
        if (INV) __builtin_amdgcn_fence(__ATOMIC_ACQUIRE, "agent");  // L1+L2 invalidate
    }
    __syncthreads();
}

// ---------------- weight prep + state init ----------------
__global__ __launch_bounds__(256) void prep_weights(const float* __restrict__ W0,
                                                    const float* __restrict__ W1,
                                                    unsigned short* W0f, unsigned short* W0i,
                                                    unsigned short* W0z, unsigned short* Wff,
                                                    unsigned short* Wii, unsigned short* W1z,
                                                    float* h, unsigned short* hb,
                                                    int* bar) {
    int job = blockIdx.x;
    if (job >= 10240) {                     // h, hb zero-init
        int i0 = (job - 10240) * 2048 + threadIdx.x;
        #pragma unroll
        for (int k = 0; k < 8; ++k) { int i = i0 + k * 256; h[i] = 0.f; hb[i] = 0; }
        return;
    }
    if (job == 0) {
        for (int i = threadIdx.x; i < 4096; i += 256) bar[i] = 0;
    }
    __shared__ float tl[32][33];
    const int tx = threadIdx.x & 31, ty = threadIdx.x >> 5;
    if (job < 6144) {                       // W0 gates: 3 x [2048 x 1024] transpose
        int g = job >> 11, r = job & 2047, kt = r >> 5, nt = r & 31;
        const float* src = W0 + (size_t)g * DK2 * DH;
        unsigned short* dst = (g == 0) ? W0f : ((g == 1) ? W0i : W0z);
        #pragma unroll
        for (int i = 0; i < 4; ++i)
            tl[ty + i * 8][tx] = src[(size_t)(kt * 32 + ty + i * 8) * DH + nt * 32 + tx];
        __syncthreads();
        #pragma unroll
        for (int i = 0; i < 4; ++i)
            dst[(size_t)(nt * 32 + ty + i * 8) * DK2 + kt * 32 + tx] = f2bf(tl[tx][ty + i * 8]);
    } else if (job < 8192) {                // W1 f,i folded: [1024][1024]
        int r = job - 6144; int g = r >> 10; r &= 1023;
        int kt = r >> 5, nt = r & 31;
        const float* src = W1 + (size_t)g * DK2 * DH;
        unsigned short* dst = (g == 0) ? Wff : Wii;
        #pragma unroll
        for (int i = 0; i < 4; ++i)
            tl[ty + i * 8][tx] = src[(size_t)(kt * 32 + ty + i * 8) * DH + nt * 32 + tx]
                               + src[(size_t)(1024 + kt * 32 + ty + i * 8) * DH + nt * 32 + tx];
        __syncthreads();
        #pragma unroll
        for (int i = 0; i < 4; ++i)
            dst[(size_t)(nt * 32 + ty + i * 8) * DH + kt * 32 + tx] = f2bf(tl[tx][ty + i * 8]);
    } else {                                // W1 z: [2048 x 1024] transpose
        int r = job - 8192; int kt = r >> 5, nt = r & 31;
        const float* src = W1 + (size_t)2 * DK2 * DH;
        #pragma unroll
        for (int i = 0; i < 4; ++i)
            tl[ty + i * 8][tx] = src[(size_t)(kt * 32 + ty + i * 8) * DH + nt * 32 + tx];
        __syncthreads();
        #pragma unroll
        for (int i = 0; i < 4; ++i)
            W1z[(size_t)(nt * 32 + ty + i * 8) * DK2 + kt * 32 + tx] = f2bf(tl[tx][ty + i * 8]);
    }
}

// ---------------- main persistent kernel ----------------
struct GruParams {
    const float* x;
    const float* b0;
    const float* b1;
    const unsigned short* W0f;      // [1024 n][2048 k]
    const unsigned short* W0i;
    const unsigned short* W0z;
    const unsigned short* Wff;      // [1024][1024] folded
    const unsigned short* Wii;
    const unsigned short* W1z;      // [1024 n][2048 k]
    float* xpre;                    // [32][128][3072] f32
    float* h;  unsigned short* hb;
    float* fg;
    unsigned short* hib;
    float* h1;
    unsigned short* hcat;           // [128][2048] bf16: [h1 | h1*i2]
    float* f2g;
    float* out;
    int* bar;
};

__global__ __launch_bounds__(NTHR) void gru_main(GruParams P) {
    const int wg   = blockIdx.x;
    const int c    = wg >> 6;          // cluster 0..3, owns batch rows [32c, 32c+32)
    const int cwg  = wg & 63;          // WG within cluster
    const int tid  = threadIdx.x;
    const int lane = tid & 63;
    const int wv   = tid >> 6;         // 0..7
    const int tile = wv & 3, ks2 = wv >> 2;   // 32x32 tiles: 4 sub-tiles x 2-way ksplit
    const int cw   = wv & 1, ks4 = wv >> 1;   // 16x32 tiles: 2 col-tiles x 4-way ksplit
    const int lr   = lane & 15;
    const int kb   = (lane >> 4) * 8;  // k-offset within frag
    const int drow = (lane >> 4) * 4;  // D-frag row base

    __shared__ float s_red[4][16][17];     // 32x32 phases (A, C)
    __shared__ float s_r2[2][3][16][17];   // 16x32 phases (B, D)

    int lg = 0;
    const int crow = c * 32;           // cluster's batch-row base

    const int gateAC = cwg >> 5, nctAC = cwg & 31;   // A/C: 2 gates x 32 col-tiles
    const int rhBD   = cwg >> 5, nctBD = cwg & 31;   // B/D: 2 row-halves x 32 col-tiles

    for (int t = 0; t < TSEQ; ++t) {
        // ---- chunk GEMM every 32 steps (cluster rows x all 3072 cols) ----
        if ((t & 31) == 0) {
            for (int j = cwg; j < 384; j += 64) {
                int tt = j / 12, cj = j % 12;          // 12 col-blocks of 256
                int g = cj >> 2;
                int gcol0 = (cj & 3) * 256 + (wv & 3) * 64;   // within-gate col base (64 cols/wave)
                int b = crow + (wv >> 2) * 16 + lr;           // 2 row-halves x 16
                const float* xp = P.x + ((size_t)b * TSEQ + (t + tt)) * DH + kb;
                const unsigned short* wt = (g == 0) ? P.W0f : ((g == 1) ? P.W0i : P.W0z);
                const unsigned short* wp = wt + (size_t)(gcol0 + lr) * DK2 + kb;
                f32x4 a0 = {0,0,0,0}, a1 = a0, a2 = a0, a3 = a0;
                #pragma unroll 2
                for (int k = 0; k < DH; k += 32) {
                    f32x4 lo = *(const f32x4*)(xp + k);
                    f32x4 hi = *(const f32x4*)(xp + k + 4);
                    short8 av;
                    av[0] = (short)f2bf(lo[0]); av[1] = (short)f2bf(lo[1]);
                    av[2] = (short)f2bf(lo[2]); av[3] = (short)f2bf(lo[3]);
                    av[4] = (short)f2bf(hi[0]); av[5] = (short)f2bf(hi[1]);
                    av[6] = (short)f2bf(hi[2]); av[7] = (short)f2bf(hi[3]);
                    short8 b0v = *(const short8*)(wp + k);
                    short8 b1v = *(const short8*)(wp + (size_t)16 * DK2 + k);
                    short8 b2v = *(const short8*)(wp + (size_t)32 * DK2 + k);
                    short8 b3v = *(const short8*)(wp + (size_t)48 * DK2 + k);
                    a0 = MFMA(av, b0v, a0);
                    a1 = MFMA(av, b1v, a1);
                    a2 = MFMA(av, b2v, a2);
                    a3 = MFMA(av, b3v, a3);
                }
                int rowb = tt * 128 + crow + (wv >> 2) * 16 + drow;
                #pragma unroll
                for (int cf = 0; cf < 4; ++cf) {
                    f32x4 acc = (cf == 0) ? a0 : ((cf == 1) ? a1 : ((cf == 2) ? a2 : a3));
                    int col = g * DH + gcol0 + cf * 16 + lr;
                    #pragma unroll
                    for (int rr = 0; rr < 4; ++rr)
                        cstoref(P.xpre + (size_t)(rowb + rr) * 3072 + col, acc[rr]);
                }
            }
            gbar<0>(P.bar, lg, wg); ++lg;
        }
        const int tq = t & 31;

        // ---- Phase A: L1 f,i = sigmoid(xpre + h @ W0{f,i}[h-part] + b0) ----
        {
            const int gate = gateAC;
            const unsigned short* wt = gate ? P.W0i : P.W0f;
            int wm = tile >> 1, wn = tile & 1;
            int rowb = crow + wm * 16, colb = nctAC * 32 + wn * 16;
            const unsigned short* ap = P.hb + (size_t)(rowb + lr) * DH + ks2 * 512 + kb;
            const unsigned short* wp = wt + (size_t)(colb + lr) * DK2 + 1024 + ks2 * 512 + kb;
            int n = colb + lr;
            short8 a[16];
            #pragma unroll
            for (int k = 0; k < 16; ++k) a[k] = *(const short8*)(ap + (size_t)k * 32);
            float xv[4] = {0,0,0,0}, hv[4] = {0,0,0,0};
            if (ks2 == 0) {
                #pragma unroll
                for (int rr = 0; rr < 4; ++rr)
                    xv[rr] = P.xpre[(size_t)(tq * 128 + rowb + drow + rr) * 3072 + gate * DH + n];
                if (gate == 1) {
                    #pragma unroll
                    for (int rr = 0; rr < 4; ++rr)
                        hv[rr] = P.h[(size_t)(rowb + drow + rr) * DH + n];
                }
            }
            short8 bw[16];
            #pragma unroll
            for (int k = 0; k < 16; ++k) bw[k] = *(const short8*)(wp + (size_t)k * 32);
            f32x4 acc = {0.f, 0.f, 0.f, 0.f};
            #pragma unroll
            for (int k = 0; k < 16; ++k) acc = MFMA(a[k], bw[k], acc);
            if (ks2 == 1) {
                s_red[tile][drow + 0][lr] = acc[0]; s_red[tile][drow + 1][lr] = acc[1];
                s_red[tile][drow + 2][lr] = acc[2]; s_red[tile][drow + 3][lr] = acc[3];
            }
            __syncthreads();
            if (ks2 == 0) {
                acc[0] += s_red[tile][drow + 0][lr]; acc[1] += s_red[tile][drow + 1][lr];
                acc[2] += s_red[tile][drow + 2][lr]; acc[3] += s_red[tile][drow + 3][lr];
                float bias = P.b0[gate * DH + n];
                #pragma unroll
                for (int rr = 0; rr < 4; ++rr) {
                    int b = rowb + drow + rr;
                    float pre = acc[rr] + xv[rr] + bias;
                    float s = 1.f / (1.f + __expf(-pre));
                    if (gate == 0) cstoref(P.fg + (size_t)b * DH + n, s);
                    else           cstoreh(P.hib + (size_t)b * DH + n, f2bf(hv[rr] * s));
                }
            }
            gbar<0>(P.bar, lg, wg); ++lg;
        }

        // ---- Phase B: L1 z = tanh(xpre_z + (h*i) @ W0z[h-part] + b0z); h1 = (1-f)h + f z ----
        {
            int rowb = crow + rhBD * 16, colb = nctBD * 32 + cw * 16;
            const unsigned short* ap = P.hib + (size_t)(rowb + lr) * DH + ks4 * 256 + kb;
            const unsigned short* wp = P.W0z + (size_t)(colb + lr) * DK2 + 1024 + ks4 * 256 + kb;
            int n = colb + lr;
            short8 a[8];
            #pragma unroll
            for (int k = 0; k < 8; ++k) a[k] = *(const short8*)(ap + (size_t)k * 32);
            float xv[4] = {0,0,0,0}, fv[4] = {0,0,0,0}, hv[4] = {0,0,0,0};
            if (ks4 == 0) {
                #pragma unroll
                for (int rr = 0; rr < 4; ++rr) {
                    int b = rowb + drow + rr;
                    xv[rr] = P.xpre[(size_t)(tq * 128 + b) * 3072 + 2 * DH + n];
                    fv[rr] = P.fg[(size_t)b * DH + n];
                    hv[rr] = P.h[(size_t)b * DH + n];
                }
            }
            short8 bw[8];
            #pragma unroll
            for (int k = 0; k < 8; ++k) bw[k] = *(const short8*)(wp + (size_t)k * 32);
            f32x4 acc = {0.f, 0.f, 0.f, 0.f};
            #pragma unroll
            for (int k = 0; k < 8; ++k) acc = MFMA(a[k], bw[k], acc);
            if (ks4 != 0) {
                s_r2[cw][ks4 - 1][drow + 0][lr] = acc[0]; s_r2[cw][ks4 - 1][drow + 1][lr] = acc[1];
                s_r2[cw][ks4 - 1][drow + 2][lr] = acc[2]; s_r2[cw][ks4 - 1][drow + 3][lr] = acc[3];
            }
            __syncthreads();
            if (ks4 == 0) {
                #pragma unroll
                for (int rr = 0; rr < 4; ++rr)
                    acc[rr] += s_r2[cw][0][drow + rr][lr] + s_r2[cw][1][drow + rr][lr]
                             + s_r2[cw][2][drow + rr][lr];
                float bias = P.b0[2 * DH + n];
                #pragma unroll
                for (int rr = 0; rr < 4; ++rr) {
                    int b = rowb + drow + rr;
                    float pre = acc[rr] + xv[rr] + bias;
                    float z = tanhf(pre);
                    float nh = (1.f - fv[rr]) * hv[rr] + fv[rr] * z;
                    cstoref(P.h1 + (size_t)b * DH + n, nh);
                    cstoreh(P.hcat + (size_t)b * DK2 + n, f2bf(nh));
                }
            }
            gbar<0>(P.bar, lg, wg); ++lg;
        }

        // ---- Phase C: L2 f2 = sigmoid(h1 @ Wff + b1f), i2 = sigmoid(h1 @ Wii + b1i) ----
        {
            const int gate = gateAC;
            const unsigned short* wt = gate ? P.Wii : P.Wff;
            int wm = tile >> 1, wn = tile & 1;
            int rowb = crow + wm * 16, colb = nctAC * 32 + wn * 16;
            const unsigned short* ap = P.hcat + (size_t)(rowb + lr) * DK2 + ks2 * 512 + kb;
            const unsigned short* wp = wt + (size_t)(colb + lr) * DH + ks2 * 512 + kb;
            int n = colb + lr;
            short8 a[16];
            #pragma unroll
            for (int k = 0; k < 16; ++k) a[k] = *(const short8*)(ap + (size_t)k * 32);
            float h1v[4] = {0,0,0,0};
            if (ks2 == 0 && gate == 1) {
                #pragma unroll
                for (int rr = 0; rr < 4; ++rr)
                    h1v[rr] = P.h1[(size_t)(rowb + drow + rr) * DH + n];
            }
            short8 bw[16];
            #pragma unroll
            for (int k = 0; k < 16; ++k) bw[k] = *(const short8*)(wp + (size_t)k * 32);
            f32x4 acc = {0.f, 0.f, 0.f, 0.f};
            #pragma unroll
            for (int k = 0; k < 16; ++k) acc = MFMA(a[k], bw[k], acc);
            if (ks2 == 1) {
                s_red[tile][drow + 0][lr] = acc[0]; s_red[tile][drow + 1][lr] = acc[1];
                s_red[tile][drow + 2][lr] = acc[2]; s_red[tile][drow + 3][lr] = acc[3];
            }
            __syncthreads();
            if (ks2 == 0) {
                acc[0] += s_red[tile][drow + 0][lr]; acc[1] += s_red[tile][drow + 1][lr];
                acc[2] += s_red[tile][drow + 2][lr]; acc[3] += s_red[tile][drow + 3][lr];
                float bias = P.b1[gate * DH + n];
                #pragma unroll
                for (int rr = 0; rr < 4; ++rr) {
                    int b = rowb + drow + rr;
                    float pre = acc[rr] + bias;
                    float s = 1.f / (1.f + __expf(-pre));
                    if (gate == 0) cstoref(P.f2g + (size_t)b * DH + n, s);
                    else           cstoreh(P.hcat + (size_t)b * DK2 + DH + n, f2bf(h1v[rr] * s));
                }
            }
            gbar<0>(P.bar, lg, wg); ++lg;
        }

        // ---- Phase D: z2 = tanh([h1 | h1*i2] @ W1z + b1z); h = (1-f2)h1 + f2 z2 ----
        {
            int rowb = crow + rhBD * 16, colb = nctBD * 32 + cw * 16;
            const unsigned short* ap = P.hcat + (size_t)(rowb + lr) * DK2 + ks4 * 512 + kb;
            const unsigned short* wp = P.W1z + (size_t)(colb + lr) * DK2 + ks4 * 512 + kb;
            int n = colb + lr;
            short8 a[16];
            #pragma unroll
            for (int k = 0; k < 16; ++k) a[k] = *(const short8*)(ap + (size_t)k * 32);
            float f2v[4] = {0,0,0,0}, h1v[4] = {0,0,0,0};
            if (ks4 == 0) {
                #pragma unroll
                for (int rr = 0; rr < 4; ++rr) {
                    int b = rowb + drow + rr;
                    f2v[rr] = P.f2g[(size_t)b * DH + n];
                    h1v[rr] = P.h1[(size_t)b * DH + n];
                }
            }
            short8 bw[16];
            #pragma unroll
            for (int k = 0; k < 16; ++k) bw[k] = *(const short8*)(wp + (size_t)k * 32);
            f32x4 acc = {0.f, 0.f, 0.f, 0.f};
            #pragma unroll
            for (int k = 0; k < 16; ++k) acc = MFMA(a[k], bw[k], acc);
            if (ks4 != 0) {
                s_r2[cw][ks4 - 1][drow + 0][lr] = acc[0]; s_r2[cw][ks4 - 1][drow + 1][lr] = acc[1];
                s_r2[cw][ks4 - 1][drow + 2][lr] = acc[2]; s_r2[cw][ks4 - 1][drow + 3][lr] = acc[3];
            }
            __syncthreads();
            if (ks4 == 0) {
                #pragma unroll
                for (int rr = 0; rr < 4; ++rr)
                    acc[rr] += s_r2[cw][0][drow + rr][lr] + s_r2[cw][1][drow + rr][lr]
                             + s_r2[cw][2][drow + rr][lr];
                float bias = P.b1[2 * DH + n];
                #pragma unroll
                for (int rr = 0; rr < 4; ++rr) {
                    int b = rowb + drow + rr;
                    float pre = acc[rr] + bias;
                    float z = tanhf(pre);
                    float nh = (1.f - f2v[rr]) * h1v[rr] + f2v[rr] * z;
                    cstoref(P.h + (size_t)b * DH + n, nh);
                    cstoreh(P.hb + (size_t)b * DH + n, f2bf(nh));
                    if (t == TSEQ - 1) P.out[(size_t)b * DH + n] = nh;  // normal store: kernel-end flush
                }
            }
            gbar<1>(P.bar, lg, wg); ++lg;   // step boundary: L2 invalidate
        }
    }
}

extern "C" void kernel_launch(void* const* d_in, const int* in_sizes, int n_in,
                              void* d_out, int out_size, void* d_ws, size_t ws_size,
                              hipStream_t stream) {
    const float* x  = (const float*)d_in[0];
    const float* W0 = (const float*)d_in[1];
    const float* b0 = (const float*)d_in[2];
    const float* W1 = (const float*)d_in[3];
    const float* b1 = (const float*)d_in[4];

    char* ws = (char*)d_ws;
    size_t off = 0;
    auto alloc = [&](size_t bytes) { void* p = ws + off; off += (bytes + 255) & ~(size_t)255; return p; };

    unsigned short* W0f = (unsigned short*)alloc((size_t)DH * DK2 * 2);
    unsigned short* W0i = (unsigned short*)alloc((size_t)DH * DK2 * 2);
    unsigned short* W0z = (unsigned short*)alloc((size_t)DH * DK2 * 2);
    unsigned short* W1z = (unsigned short*)alloc((size_t)DH * DK2 * 2);
    unsigned short* Wff = (unsigned short*)alloc((size_t)DH * DH * 2);
    unsigned short* Wii = (unsigned short*)alloc((size_t)DH * DH * 2);
    float* xpre = (float*)alloc((size_t)32 * 128 * 3072 * 4);
    float* h    = (float*)alloc((size_t)BB * DH * 4);
    unsigned short* hb = (unsigned short*)alloc((size_t)BB * DH * 2);
    float* fg   = (float*)alloc((size_t)BB * DH * 4);
    unsigned short* hib = (unsigned short*)alloc((size_t)BB * DH * 2);
    float* h1   = (float*)alloc((size_t)BB * DH * 4);
    unsigned short* hcat = (unsigned short*)alloc((size_t)BB * DK2 * 2);
    float* f2g  = (float*)alloc((size_t)BB * DH * 4);
    int* bar    = (int*)alloc(16384);
    (void)ws_size; (void)in_sizes; (void)n_in; (void)out_size;

    prep_weights<<<10304, 256, 0, stream>>>(W0, W1, W0f, W0i, W0z, Wff, Wii, W1z,
                                            h, hb, bar);

    GruParams p;
    p.x = x; p.b0 = b0; p.b1 = b1;
    p.W0f = W0f; p.W0i = W0i; p.W0z = W0z; p.Wff = Wff; p.Wii = Wii; p.W1z = W1z;
    p.xpre = xpre; p.h = h; p.hb = hb; p.fg = fg; p.hib = hib;
    p.h1 = h1; p.hcat = hcat; p.f2g = f2g;
    p.out = (float*)d_out;
    p.bar = bar;

    void* args[] = { &p };
    hipLaunchCooperativeKernel((const void*)gru_main, dim3(NWG), dim3(NTHR), args, 0, stream);
}